// Round 16
// baseline (433.491 us; speedup 1.0000x reference)
//
#include <hip/hip_runtime.h>
#include <hip/hip_bf16.h>
#include <math.h>

#define N_TOK 8192
#define DIM   1024
#define NEXP  64
#define TOPK  8
#define CAPF  2048     // per-expert list capacity (mean 1024, ~34 sigma headroom)

typedef __attribute__((ext_vector_type(8))) short short8;
typedef __attribute__((ext_vector_type(4))) float floatx4;
typedef unsigned int u32;

static __device__ __forceinline__ short f2bf(float f) {
    union { float f; unsigned u; } c; c.f = f;
    unsigned r = c.u + 0x7FFF + ((c.u >> 16) & 1);   // RNE
    return (short)(r >> 16);
}
static __device__ __forceinline__ float bf2f(unsigned s) {   // low 16 bits = bf16
    union { unsigned u; float f; } c; c.u = s << 16;
    return c.f;
}
static __device__ __forceinline__ short8 pack8(float4 a, float4 b) {
    short8 o;
    o[0]=f2bf(a.x); o[1]=f2bf(a.y); o[2]=f2bf(a.z); o[3]=f2bf(a.w);
    o[4]=f2bf(b.x); o[5]=f2bf(b.y); o[6]=f2bf(b.z); o[7]=f2bf(b.w);
    return o;
}
// async global->LDS, 16B/lane; lds ptr wave-uniform (HW: base + lane*16)
static __device__ __forceinline__ void gll16(const short* g, short* l) {
    __builtin_amdgcn_global_load_lds(
        (const __attribute__((address_space(1))) u32*)(const void*)g,
        (__attribute__((address_space(3))) u32*)(void*)l, 16, 0, 0);
}
// inline-asm LDS b128 read: opaque to alias analysis (no auto vmcnt drains)
static __device__ __forceinline__ short8 ds_read128(const short* p) {
    short8 v;
    asm volatile("ds_read_b128 %0, %1"
                 : "=v"(v)
                 : "v"((const __attribute__((address_space(3))) short*)p));
    return v;
}

// ---- fused prep: router + h->bf16 + inline top-8 (blocks 0..255) | W->bf16 (rest) ----
__global__ __launch_bounds__(256) void k_prep(
    const float* __restrict__ h, const float* __restrict__ gw,
    float* __restrict__ logits, short* __restrict__ hb,
    const float* __restrict__ ew, short* __restrict__ wb,
    int* __restrict__ tki, float* __restrict__ tkw)
{
    __shared__ float hs[32 * 68];
    __shared__ float gs[64 * 68];
    int bx = blockIdx.x;
    int tid = threadIdx.x;

    if (bx >= 256) {   // W convert chunk (independent, BW-bound)
        size_t i = ((size_t)(bx - 256) * 256 + tid) * 8;
        float4 f0 = *(const float4*)(ew + i);
        float4 f1 = *(const float4*)(ew + i + 4);
        *(short8*)(wb + i) = pack8(f0, f1);
        return;
    }

    int t0 = bx * 32;
    int tm = tid & 15;
    int en = tid >> 4;
    float acc[2][4] = {{0.f,0.f,0.f,0.f},{0.f,0.f,0.f,0.f}};

    for (int k0 = 0; k0 < DIM; k0 += 64) {
        {
            int row = tid >> 3, seg = (tid & 7) * 8;
            const float* src = h + (size_t)(t0 + row) * DIM + k0 + seg;
            float4 f0 = *(const float4*)src;
            float4 f1 = *(const float4*)(src + 4);
            *(float4*)&hs[row*68 + seg]     = f0;
            *(float4*)&hs[row*68 + seg + 4] = f1;
            if (hb)
                *(short8*)(hb + (size_t)(t0 + row) * DIM + k0 + seg) = pack8(f0, f1);
        }
        {
            int row = tid >> 2, seg = (tid & 3) * 16;
            const float* src = gw + (size_t)row * DIM + k0 + seg;
            float4* dst = (float4*)&gs[row*68 + seg];
            #pragma unroll
            for (int j = 0; j < 4; ++j) dst[j] = *(const float4*)(src + j*4);
        }
        __syncthreads();
        #pragma unroll
        for (int k4 = 0; k4 < 16; ++k4) {
            float4 h0 = *(const float4*)&hs[tm*68 + k4*4];
            float4 h1 = *(const float4*)&hs[(tm+16)*68 + k4*4];
            #pragma unroll
            for (int j = 0; j < 4; ++j) {
                float4 g = *(const float4*)&gs[(en + 16*j)*68 + k4*4];
                acc[0][j] += h0.x*g.x + h0.y*g.y + h0.z*g.z + h0.w*g.w;
                acc[1][j] += h1.x*g.x + h1.y*g.y + h1.z*g.z + h1.w*g.w;
            }
        }
        __syncthreads();
    }
    #pragma unroll
    for (int r = 0; r < 2; ++r)
        #pragma unroll
        for (int j = 0; j < 4; ++j)
            logits[(size_t)(t0 + tm + 16*r) * NEXP + en + 16*j] = acc[r][j];

    // ---- fused top-8: stage logit rows in LDS, wave-per-token reduce ----
    float* sl = hs;    // reuse as [32][65]
    #pragma unroll
    for (int r = 0; r < 2; ++r)
        #pragma unroll
        for (int j = 0; j < 4; ++j)
            sl[(tm + 16*r)*65 + en + 16*j] = acc[r][j];
    __syncthreads();

    int wv = tid >> 6, lane = tid & 63;
    for (int ti = 0; ti < 8; ++ti) {
        int tok = wv*8 + ti;
        float x = sl[tok*65 + lane];
        float m = x;
        #pragma unroll
        for (int off = 32; off; off >>= 1) m = fmaxf(m, __shfl_xor(m, off));
        float p = expf(x - m);
        float s = p;
        #pragma unroll
        for (int off = 32; off; off >>= 1) s += __shfl_xor(s, off);
        float cur = p / s;
        for (int k = 0; k < TOPK; ++k) {
            float v = cur; int idx = lane;
            #pragma unroll
            for (int off = 32; off; off >>= 1) {
                float ov = __shfl_xor(v, off);
                int   oi = __shfl_xor(idx, off);
                if (ov > v || (ov == v && oi < idx)) { v = ov; idx = oi; }
            }
            if (lane == idx) cur = -1.0f;
            if (lane == 0) {
                tki[(size_t)(t0 + tok) * TOPK + k] = idx;
                tkw[(size_t)(t0 + tok) * TOPK + k] = v;
            }
        }
    }
}

// ---------------- compaction into token-sorted per-expert lists ----------------
__global__ void k_topk2(const int* __restrict__ tki, const float* __restrict__ tkw,
                        int* __restrict__ counts, int* __restrict__ tlist,
                        float* __restrict__ wlist, int cap) {
    int e = blockIdx.x, tid = threadIdx.x, lane = tid & 63, wv = tid >> 6;
    __shared__ int wtot[4];
    __shared__ int carry_s;
    if (tid == 0) carry_s = 0;
    __syncthreads();

    for (int c0 = 0; c0 < N_TOK * TOPK; c0 += 1024) {
        int i = c0 + tid * 4;
        int4 v = *(const int4*)(tki + i);
        int m0 = (v.x == e), m1 = (v.y == e), m2 = (v.z == e), m3 = (v.w == e);
        int mc = m0 + m1 + m2 + m3;
        int sc = mc;
        #pragma unroll
        for (int off = 1; off < 64; off <<= 1) {
            int o = __shfl_up(sc, off);
            if (lane >= off) sc += o;
        }
        if (lane == 63) wtot[wv] = sc;
        int excl = sc - mc;
        __syncthreads();
        int wbase = 0;
        #pragma unroll
        for (int j = 0; j < 4; ++j) if (j < wv) wbase += wtot[j];
        int tot = wtot[0] + wtot[1] + wtot[2] + wtot[3];
        int pos = carry_s + wbase + excl;
        if (m0) { if (pos < cap) { tlist[(size_t)e*cap+pos] = i;   wlist[(size_t)e*cap+pos] = tkw[i];   } pos++; }
        if (m1) { if (pos < cap) { tlist[(size_t)e*cap+pos] = i+1; wlist[(size_t)e*cap+pos] = tkw[i+1]; } pos++; }
        if (m2) { if (pos < cap) { tlist[(size_t)e*cap+pos] = i+2; wlist[(size_t)e*cap+pos] = tkw[i+2]; } pos++; }
        if (m3) { if (pos < cap) { tlist[(size_t)e*cap+pos] = i+3; wlist[(size_t)e*cap+pos] = tkw[i+3]; } pos++; }
        __syncthreads();
        if (tid == 0) carry_s += tot;
        __syncthreads();
    }
    if (tid == 0) counts[e] = min(carry_s, cap);
    __syncthreads();
    int cnt = min(carry_s, cap);
    int padded = (cnt + 255) & ~255;
    for (int i = cnt + tid; i < padded; i += 256) {
        tlist[(size_t)e*cap + i] = 0;
        wlist[(size_t)e*cap + i] = 0.0f;
    }
}

// ======== tier-3: 256x256 Gray-code 4-phase, REGISTER-PIPELINED reads (m201 skew) ========
// Reads for phase p+1 issued at END of phase p (pre-barrier skew); fragment regs double-
// buffered (afA/afB per phase parity, bfA=k0/bfB=k1). Staging: B01@ph0, B23+A0@ph1,
// A1@ph2. vmcnt ledger {0,2,6,2} steady; tail full-drain. LDS chunk pos = c^(row&7).
#define PADW 264

__global__ __launch_bounds__(512) void k_moe256(
    const short* __restrict__ hb, const short* __restrict__ wb,
    const int* __restrict__ counts, const int* __restrict__ tlist,
    const float* __restrict__ wlist, unsigned short* __restrict__ contrib, int cap)
{
    __shared__ short As[2 * 16384];   // [slot][256 rows][64]
    __shared__ short Bs[2 * 16384];
    __shared__ int   slots[256];
    __shared__ float wgts[256];

    int bx = blockIdx.x;
    int g  = ((bx >> 6) << 3) | (bx & 7);   // 0..255 = e*4+nt
    int mt = (bx >> 3) & 7;
    int e  = g >> 2;
    int n0 = (g & 3) * 256;
    int cnt = counts[e]; if (cnt > cap) cnt = cap;
    if (mt * 256 >= cnt) return;

    int tid = threadIdx.x, lane = tid & 63, w = tid >> 6;   // w 0..7
    int wm = w >> 2, wn = w & 3;                            // 2m x 4n waves

    if (tid < 256) {
        size_t base = (size_t)e * cap + (size_t)mt * 256 + tid;
        slots[tid] = tlist[base];
        wgts[tid]  = wlist[base];
    }
    __syncthreads();

    // B staging: load i covers rows (w*4+i)*8..+7, full K, pre-swizzled chunk
    const short* baddr[4];
    #pragma unroll
    for (int i = 0; i < 4; ++i) {
        int row = (w*4 + i)*8 + (lane >> 3);
        int gch = (lane & 7) ^ (row & 7);
        baddr[i] = wb + ((size_t)e << 20) + (size_t)(n0 + row) * DIM + gch*8;
    }
    // A staging by m-half: wave stages groups g=w*2+j within each half-class
    const short* aaddr2[2][2];
    int baseA[2][2];
    #pragma unroll
    for (int mh = 0; mh < 2; ++mh)
        #pragma unroll
        for (int j = 0; j < 2; ++j) {
            int gg = w*2 + j;
            int br = mh*64 + gg*8 + ((gg >= 8) ? 64 : 0);
            baseA[mh][j] = br * 64;
            int r8 = lane >> 3;
            int ch = (lane & 7) ^ r8;
            aaddr2[mh][j] = hb + (size_t)(slots[br + r8] >> 3) * DIM + ch*8;
        }

    floatx4 acc[8][4];   // acc[mh*4+mm][nn]: row wm*128+mh*64+mm*16, col wn*64+nn*16
    #pragma unroll
    for (int i = 0; i < 8; ++i)
        #pragma unroll
        for (int j = 0; j < 4; ++j) acc[i][j] = (floatx4)0.0f;

    short8 afA[4], afB[4], bfA[4], bfB[4];

#define RD_A(DST, MH, KK, SLP) { int rr = lane & 15; int gch = (KK)*4 + (lane >> 4); \
    _Pragma("unroll") for (int mm = 0; mm < 4; ++mm) { \
        int rowa = wm*128 + (MH)*64 + mm*16 + rr; \
        DST[mm] = ds_read128(&(SLP)[rowa*64 + ((gch ^ (rowa & 7)) * 8)]); } }
#define RD_B(DST, KK, SLP) { int rr = lane & 15; int gch = (KK)*4 + (lane >> 4); \
    _Pragma("unroll") for (int nn = 0; nn < 4; ++nn) { \
        int rowb = wn*64 + nn*16 + rr; \
        DST[nn] = ds_read128(&(SLP)[rowb*64 + ((gch ^ (rowb & 7)) * 8)]); } }
#define MM16(AF, BF, MH) { \
    _Pragma("unroll") for (int mm = 0; mm < 4; ++mm) \
        _Pragma("unroll") for (int nn = 0; nn < 4; ++nn) \
            acc[(MH)*4+mm][nn] = __builtin_amdgcn_mfma_f32_16x16x32_bf16( \
                AF[mm], BF[nn], acc[(MH)*4+mm][nn], 0, 0, 0); }
#define PH(NW, AF, BF, MH, WSTG, RSTG) { \
    asm volatile("s_waitcnt vmcnt(" #NW ")" ::: "memory"); \
    __builtin_amdgcn_s_barrier(); \
    asm volatile("s_waitcnt lgkmcnt(0)" ::: "memory"); \
    __builtin_amdgcn_sched_barrier(0); \
    __builtin_amdgcn_s_setprio(1); MM16(AF, BF, MH); __builtin_amdgcn_s_setprio(0); \
    WSTG; RSTG; }

    // prologue: stage tile 0 -> slot 0, drain, publish, pre-read ph0 frags
    #pragma unroll
    for (int i = 0; i < 4; ++i) gll16(baddr[i], &Bs[(w*4 + i)*512]);
    gll16(aaddr2[0][0], &As[baseA[0][0]]);
    gll16(aaddr2[0][1], &As[baseA[0][1]]);
    gll16(aaddr2[1][0], &As[baseA[1][0]]);
    gll16(aaddr2[1][1], &As[baseA[1][1]]);
    asm volatile("s_waitcnt vmcnt(0)" ::: "memory");
    __builtin_amdgcn_s_barrier();
    { const short* Ac = As; const short* Bc = Bs;
      RD_A(afA, 0, 0, Ac); RD_B(bfA, 0, Bc); }

    for (int t = 0; t < 15; ++t) {
        const int cs = t & 1;
        const short* Ac = &As[cs*16384];
        const short* Bc = &Bs[cs*16384];
        const short* An = &As[(cs^1)*16384];
        const short* Bn = &Bs[(cs^1)*16384];
        short* Anw = &As[(cs^1)*16384];
        short* Bnw = &Bs[(cs^1)*16384];
        const int koff = (t+1)*64;
        // ph0 (k0,mh0): stage B01(t+1); pre-read A(mh1,k0)
        PH(0, afA, bfA, 0,
           { gll16(baddr[0]+koff, Bnw + (w*4+0)*512);
             gll16(baddr[1]+koff, Bnw + (w*4+1)*512); },
           { RD_A(afB, 1, 0, Ac); });
        // ph1 (k0,mh1): stage B23+A0(t+1); pre-read A(mh1,k1) + B(k1)
        PH(2, afB, bfA, 1,
           { gll16(baddr[2]+koff, Bnw + (w*4+2)*512);
             gll16(baddr[3]+koff, Bnw + (w*4+3)*512);
             gll16(aaddr2[0][0]+koff, Anw + baseA[0][0]);
             gll16(aaddr2[0][1]+koff, Anw + baseA[0][1]); },
           { RD_A(afA, 1, 1, Ac); RD_B(bfB, 1, Bc); });
        // ph2 (k1,mh1): stage A1(t+1); pre-read A(mh0,k1)
        PH(6, afA, bfB, 1,
           { gll16(aaddr2[1][0]+koff, Anw + baseA[1][0]);
             gll16(aaddr2[1][1]+koff, Anw + baseA[1][1]); },
           { RD_A(afB, 0, 1, Ac); });
        // ph3 (k1,mh0): pre-read next tile's (mh0,k0)+B(k0) from other slot
        PH(2, afB, bfB, 0, {},
           { RD_A(afA, 0, 0, An); RD_B(bfA, 0, Bn); });
    }
    {   // tail: tile 15 (slot 1), no staging, full drains
        const short* Ac = &As[16384];
        const short* Bc = &Bs[16384];
        PH(0, afA, bfA, 0, {}, { RD_A(afB, 1, 0, Ac); });
        PH(0, afB, bfA, 1, {}, { RD_A(afA, 1, 1, Ac); RD_B(bfB, 1, Bc); });
        PH(0, afA, bfB, 1, {}, { RD_A(afB, 0, 1, Ac); });
        PH(0, afB, bfB, 0, {}, {});
    }
#undef PH
#undef MM16
#undef RD_A
#undef RD_B

    // epilogue: LDS transpose (reuse As) -> 32B-contiguous bf16 stores
    short* pad = As;    // 32*PADW = 8448 shorts <= 32768
    int cgrp = lane >> 4, ccol = lane & 15;
    #pragma unroll
    for (int q8 = 0; q8 < 8; ++q8) {
        int mh = q8 >> 2, mm = q8 & 3;
        __syncthreads();
        #pragma unroll
        for (int r = 0; r < 4; ++r) {
            int sub = cgrp*4 + r;
            float wgt = wgts[wm*128 + mh*64 + mm*16 + sub];
            #pragma unroll
            for (int nn = 0; nn < 4; ++nn)
                pad[(wm*16 + sub)*PADW + wn*64 + nn*16 + ccol] =
                    f2bf(wgt * acc[q8][nn][r]);
        }
        __syncthreads();
        int prow = tid >> 4, piece = tid & 15;
        int wm2 = prow >> 4, sub = prow & 15;
        int grow = wm2*128 + mh*64 + mm*16 + sub;
        if (wgts[grow] != 0.0f) {
            size_t base = (size_t)slots[grow] * DIM + n0 + piece*16;
            uint4 v0 = *(const uint4*)&pad[prow*PADW + piece*16];
            uint4 v1 = *(const uint4*)&pad[prow*PADW + piece*16 + 8];
            *(uint4*)&contrib[base]     = v0;
            *(uint4*)&contrib[base + 8] = v1;
        }
    }
}

// ---------------- fallback gathered GEMM (tiers 0-1, atomics) ----------------
#define BMo 256
#define BNo 128
#define LDT 72
template<bool AB>
__global__ __launch_bounds__(512) void k_moe(
    const float* __restrict__ h, const short* __restrict__ hb,
    const float* __restrict__ ew,
    const int* __restrict__ counts, const int* __restrict__ tlist,
    const float* __restrict__ wlist, float* __restrict__ out, int cap)
{
    __shared__ short As[BMo * LDT];
    __shared__ short Bs[BNo * LDT];
    __shared__ int   slots[BMo];
    __shared__ float wgts[BMo];

    int e  = blockIdx.x >> 3;
    int n0 = (blockIdx.x & 7) * BNo;
    int cnt = counts[e];
    if (cnt > cap) cnt = cap;
    if (cnt == 0) return;
    int ntiles = (cnt + BMo - 1) / BMo;

    int tid  = threadIdx.x;
    int lane = tid & 63;
    int wv = tid >> 6;
    int wm = wv >> 1;
    int wn = wv & 1;

    int arow = tid >> 1;
    int acol = (tid & 1) * 32;
    int brow = tid >> 2;
    int bcol = (tid & 3) * 16;
    const float* wbasef = ew + ((size_t)e << 20) + (size_t)(n0 + brow) * DIM + bcol;

    float4 raf[8];
    uint4  rab[4];
    float4 rbf[4];

    for (int mtt = 0; mtt < ntiles; ++mtt) {
        __syncthreads();
        if (tid < BMo) {
            size_t base = (size_t)e * cap + (size_t)mtt * BMo + tid;
            slots[tid] = tlist[base];
            wgts[tid]  = wlist[base];
        }
        __syncthreads();

        floatx4 acc[4][4];
        #pragma unroll
        for (int i = 0; i < 4; ++i)
            #pragma unroll
            for (int j = 0; j < 4; ++j) acc[i][j] = (floatx4)0.0f;

        size_t trow = (size_t)(slots[arow] >> 3);
        const float* hrowf = h  + trow * DIM + acol;
        const short* hrowb = hb + trow * DIM + acol;

        if constexpr (AB) {
            #pragma unroll
            for (int j = 0; j < 4; ++j) rab[j] = *(const uint4*)(hrowb + j*8);
        } else {
            #pragma unroll
            for (int j = 0; j < 4; ++j) {
                raf[2*j]   = *(const float4*)(hrowf + j*8);
                raf[2*j+1] = *(const float4*)(hrowf + j*8 + 4);
            }
        }
        #pragma unroll
        for (int j = 0; j < 4; ++j) rbf[j] = *(const float4*)(wbasef + j*4);

        for (int k0 = 0; k0 < DIM; k0 += 64) {
            if constexpr (AB) {
                #pragma unroll
                for (int j = 0; j < 4; ++j)
                    *(uint4*)&As[arow*LDT + acol + j*8] = rab[j];
            } else {
                #pragma unroll
                for (int j = 0; j < 4; ++j)
                    *(short8*)&As[arow*LDT + acol + j*8] = pack8(raf[2*j], raf[2*j+1]);
            }
            #pragma unroll
            for (int j = 0; j < 2; ++j)
                *(short8*)&Bs[brow*LDT + bcol + j*8] = pack8(rbf[2*j], rbf[2*j+1]);
            __syncthreads();

            int kn = k0 + 64;
            if (kn < DIM) {
                if constexpr (AB) {
                    #pragma unroll
                    for (int j = 0; j < 4; ++j) rab[j] = *(const uint4*)(hrowb + kn + j*8);
                } else {
                    #pragma unroll
                    for (int j = 0; j < 4; ++j) {
                        raf[2*j]   = *(const float4*)(hrowf + kn + j*8);
                        raf[2*j+1] = *(const float4*)(hrowf + kn + j*8 + 4);
                    }
                }
                #pragma unroll
                for (int j = 0; j < 4; ++j) rbf[j] = *(const float4*)(wbasef + kn + j*4);
            }

            #pragma unroll
            for (int s = 0; s < 2; ++s) {
                int ko = s*32 + (lane >> 4) * 8;
                int rr = lane & 15;
                short8 af[4], bfr[4];
                #pragma unroll
                for (int mm = 0; mm < 4; ++mm)
                    af[mm] = *(const short8*)&As[(wm*64 + mm*16 + rr)*LDT + ko];
                #pragma unroll
                for (int nn = 0; nn < 4; ++nn)
                    bfr[nn] = *(const short8*)&Bs[(wn*64 + nn*16 + rr)*LDT + ko];
                #pragma unroll
                for (int mm = 0; mm < 4; ++mm)
                    #pragma unroll
                    for (int nn = 0; nn < 4; ++nn)
                        acc[mm][nn] = __builtin_amdgcn_mfma_f32_16x16x32_bf16(
                            af[mm], bfr[nn], acc[mm][nn], 0, 0, 0);
            }
            __syncthreads();
        }

        int cgrp = lane >> 4;
        int ccol = lane & 15;
        #pragma unroll
        for (int mm = 0; mm < 4; ++mm) {
            #pragma unroll
            for (int r = 0; r < 4; ++r) {
                int row = wm*64 + mm*16 + cgrp*4 + r;
                float wgt = wgts[row];
                if (wgt != 0.0f) {
                    size_t tok = (size_t)(slots[row] >> 3);
                    #pragma unroll
                    for (int nn = 0; nn < 4; ++nn) {
                        int col = n0 + wn*64 + nn*16 + ccol;
                        atomicAdd(&out[tok * DIM + col], wgt * acc[mm][nn][r]);
                    }
                }
            }
        }
    }
}

// ---------------- gather: out[t] = sum_k contrib[t*8+k] (16B loads) ----------------
__global__ __launch_bounds__(128) void k_gather(
    const unsigned short* __restrict__ contrib, float* __restrict__ out) {
    int t = blockIdx.x;
    int c = threadIdx.x * 8;
    float s[8] = {0,0,0,0,0,0,0,0};
    #pragma unroll
    for (int k = 0; k < TOPK; ++k) {
        uint4 v = *(const uint4*)(contrib + ((size_t)t * TOPK + k) * DIM + c);
        s[0] += bf2f(v.x & 0xffff); s[1] += bf2f(v.x >> 16);
        s[2] += bf2f(v.y & 0xffff); s[3] += bf2f(v.y >> 16);
        s[4] += bf2f(v.z & 0xffff); s[5] += bf2f(v.z >> 16);
        s[6] += bf2f(v.w & 0xffff); s[7] += bf2f(v.w >> 16);
    }
    float4 o0 = {s[0], s[1], s[2], s[3]};
    float4 o1 = {s[4], s[5], s[6], s[7]};
    *(float4*)(out + (size_t)t * DIM + c)     = o0;
    *(float4*)(out + (size_t)t * DIM + c + 4) = o1;
}

extern "C" void kernel_launch(void* const* d_in, const int* in_sizes, int n_in,
                              void* d_out, int out_size, void* d_ws, size_t ws_size,
                              hipStream_t stream) {
    const float* h  = (const float*)d_in[0];
    const float* gw = (const float*)d_in[1];
    const float* ew = (const float*)d_in[2];
    float* out    = (float*)d_out;
    float* logits = out + (size_t)N_TOK * DIM;

    const size_t SZ_TK   = (size_t)N_TOK * TOPK * 4;
    const size_t SZ_HB   = (size_t)N_TOK * DIM * 2;
    const size_t SZ_WB   = (size_t)NEXP * DIM * DIM * 2;
    const size_t SZ_CT   = (size_t)N_TOK * TOPK * DIM * 2;
    const size_t SZ_LIST = (size_t)CAPF * NEXP * 4;

    size_t need_base = 4096 + 2*SZ_LIST + 2*SZ_TK + SZ_HB;
    size_t need_t3   = need_base + SZ_WB + SZ_CT;

    int tier;
    long cap = CAPF;
    if      (ws_size >= need_t3)   tier = 3;
    else if (ws_size >= need_base) tier = 1;
    else {
        tier = 0;
        size_t avail = (ws_size > 4096 + 2*SZ_TK) ? ws_size - 4096 - 2*SZ_TK : 0;
        cap = (long)(avail / ((size_t)NEXP * 8));
        cap &= ~255L;
        if (cap > N_TOK) cap = N_TOK;
    }

    char* ws = (char*)d_ws;
    size_t off = 0;
    int*   counts = (int*)(ws + off);  off += 4096;
    int*   tlist  = (int*)(ws + off);  off += (size_t)cap * NEXP * 4;
    float* wlist  = (float*)(ws + off); off += (size_t)cap * NEXP * 4;
    int*   tki    = (int*)(ws + off);  off += SZ_TK;
    float* tkw    = (float*)(ws + off); off += SZ_TK;
    short* hb     = (short*)(ws + off); if (tier >= 1) off += SZ_HB;
    short* wbuf   = (short*)(ws + off); if (tier >= 3) off += SZ_WB;
    unsigned short* contrib = (unsigned short*)(ws + off);

    if (cap >= 256 && tier < 3)
        hipMemsetAsync(out, 0, (size_t)N_TOK*DIM*4, stream);

    unsigned prep_blocks = 256 + (tier >= 3 ? (unsigned)((size_t)NEXP*DIM*DIM/(256*8)) : 0);
    k_prep<<<dim3(prep_blocks), 256, 0, stream>>>(
        h, gw, logits, (tier >= 1 && cap >= 256) ? hb : (short*)nullptr, ew, wbuf,
        tki, tkw);

    if (cap < 256) return;

    k_topk2<<<dim3(NEXP), 256, 0, stream>>>(tki, tkw, counts, tlist, wlist, (int)cap);

    if (tier == 3) {
        k_moe256<<<dim3(32 * 64), 512, 0, stream>>>(
            hb, wbuf, counts, tlist, wlist, contrib, (int)cap);
        k_gather<<<dim3(N_TOK), 128, 0, stream>>>(contrib, out);
    } else if (tier == 1) {
        k_moe<true><<<dim3(NEXP*8), 512, 0, stream>>>(
            h, hb, ew, counts, tlist, wlist, out, (int)cap);
    } else {
        k_moe<false><<<dim3(NEXP*8), 512, 0, stream>>>(
            h, hb, ew, counts, tlist, wlist, out, (int)cap);
    }
}

// Round 17
// 407.608 us; speedup vs baseline: 1.0635x; 1.0635x over previous
//
#include <hip/hip_runtime.h>
#include <hip/hip_bf16.h>
#include <math.h>

#define N_TOK 8192
#define DIM   1024
#define NEXP  64
#define TOPK  8
#define CAPF  2048     // per-expert list capacity (mean 1024, ~34 sigma headroom)

typedef __attribute__((ext_vector_type(8))) short short8;
typedef __attribute__((ext_vector_type(4))) float floatx4;
typedef unsigned int u32;

static __device__ __forceinline__ short f2bf(float f) {
    union { float f; unsigned u; } c; c.f = f;
    unsigned r = c.u + 0x7FFF + ((c.u >> 16) & 1);   // RNE
    return (short)(r >> 16);
}
static __device__ __forceinline__ float bf2f(unsigned s) {   // low 16 bits = bf16
    union { unsigned u; float f; } c; c.u = s << 16;
    return c.f;
}
static __device__ __forceinline__ short8 pack8(float4 a, float4 b) {
    short8 o;
    o[0]=f2bf(a.x); o[1]=f2bf(a.y); o[2]=f2bf(a.z); o[3]=f2bf(a.w);
    o[4]=f2bf(b.x); o[5]=f2bf(b.y); o[6]=f2bf(b.z); o[7]=f2bf(b.w);
    return o;
}
// async global->LDS, 16B/lane; lds ptr wave-uniform (HW: base + lane*16)
static __device__ __forceinline__ void gll16(const short* g, short* l) {
    __builtin_amdgcn_global_load_lds(
        (const __attribute__((address_space(1))) u32*)(const void*)g,
        (__attribute__((address_space(3))) u32*)(void*)l, 16, 0, 0);
}
// inline-asm LDS b128 read: opaque to alias analysis (no auto vmcnt drains)
static __device__ __forceinline__ short8 ds_read128(const short* p) {
    short8 v;
    asm volatile("ds_read_b128 %0, %1"
                 : "=v"(v)
                 : "v"((const __attribute__((address_space(3))) short*)p));
    return v;
}

// ---- fused prep: router + h->bf16 + inline top-8 (blocks 0..255) | W->bf16 (rest) ----
__global__ __launch_bounds__(256) void k_prep(
    const float* __restrict__ h, const float* __restrict__ gw,
    float* __restrict__ logits, short* __restrict__ hb,
    const float* __restrict__ ew, short* __restrict__ wb,
    int* __restrict__ tki, float* __restrict__ tkw)
{
    __shared__ float hs[32 * 68];
    __shared__ float gs[64 * 68];
    int bx = blockIdx.x;
    int tid = threadIdx.x;

    if (bx >= 256) {   // W convert chunk (independent, BW-bound)
        size_t i = ((size_t)(bx - 256) * 256 + tid) * 8;
        float4 f0 = *(const float4*)(ew + i);
        float4 f1 = *(const float4*)(ew + i + 4);
        *(short8*)(wb + i) = pack8(f0, f1);
        return;
    }

    int t0 = bx * 32;
    int tm = tid & 15;
    int en = tid >> 4;
    float acc[2][4] = {{0.f,0.f,0.f,0.f},{0.f,0.f,0.f,0.f}};

    for (int k0 = 0; k0 < DIM; k0 += 64) {
        {
            int row = tid >> 3, seg = (tid & 7) * 8;
            const float* src = h + (size_t)(t0 + row) * DIM + k0 + seg;
            float4 f0 = *(const float4*)src;
            float4 f1 = *(const float4*)(src + 4);
            *(float4*)&hs[row*68 + seg]     = f0;
            *(float4*)&hs[row*68 + seg + 4] = f1;
            if (hb)
                *(short8*)(hb + (size_t)(t0 + row) * DIM + k0 + seg) = pack8(f0, f1);
        }
        {
            int row = tid >> 2, seg = (tid & 3) * 16;
            const float* src = gw + (size_t)row * DIM + k0 + seg;
            float4* dst = (float4*)&gs[row*68 + seg];
            #pragma unroll
            for (int j = 0; j < 4; ++j) dst[j] = *(const float4*)(src + j*4);
        }
        __syncthreads();
        #pragma unroll
        for (int k4 = 0; k4 < 16; ++k4) {
            float4 h0 = *(const float4*)&hs[tm*68 + k4*4];
            float4 h1 = *(const float4*)&hs[(tm+16)*68 + k4*4];
            #pragma unroll
            for (int j = 0; j < 4; ++j) {
                float4 g = *(const float4*)&gs[(en + 16*j)*68 + k4*4];
                acc[0][j] += h0.x*g.x + h0.y*g.y + h0.z*g.z + h0.w*g.w;
                acc[1][j] += h1.x*g.x + h1.y*g.y + h1.z*g.z + h1.w*g.w;
            }
        }
        __syncthreads();
    }
    #pragma unroll
    for (int r = 0; r < 2; ++r)
        #pragma unroll
        for (int j = 0; j < 4; ++j)
            logits[(size_t)(t0 + tm + 16*r) * NEXP + en + 16*j] = acc[r][j];

    // ---- fused top-8: stage logit rows in LDS, wave-per-token reduce ----
    float* sl = hs;    // reuse as [32][65]
    #pragma unroll
    for (int r = 0; r < 2; ++r)
        #pragma unroll
        for (int j = 0; j < 4; ++j)
            sl[(tm + 16*r)*65 + en + 16*j] = acc[r][j];
    __syncthreads();

    int wv = tid >> 6, lane = tid & 63;
    for (int ti = 0; ti < 8; ++ti) {
        int tok = wv*8 + ti;
        float x = sl[tok*65 + lane];
        float m = x;
        #pragma unroll
        for (int off = 32; off; off >>= 1) m = fmaxf(m, __shfl_xor(m, off));
        float p = expf(x - m);
        float s = p;
        #pragma unroll
        for (int off = 32; off; off >>= 1) s += __shfl_xor(s, off);
        float cur = p / s;
        for (int k = 0; k < TOPK; ++k) {
            float v = cur; int idx = lane;
            #pragma unroll
            for (int off = 32; off; off >>= 1) {
                float ov = __shfl_xor(v, off);
                int   oi = __shfl_xor(idx, off);
                if (ov > v || (ov == v && oi < idx)) { v = ov; idx = oi; }
            }
            if (lane == idx) cur = -1.0f;
            if (lane == 0) {
                tki[(size_t)(t0 + tok) * TOPK + k] = idx;
                tkw[(size_t)(t0 + tok) * TOPK + k] = v;
            }
        }
    }
}

// ---------------- compaction into token-sorted per-expert lists ----------------
__global__ void k_topk2(const int* __restrict__ tki, const float* __restrict__ tkw,
                        int* __restrict__ counts, int* __restrict__ tlist,
                        float* __restrict__ wlist, int cap) {
    int e = blockIdx.x, tid = threadIdx.x, lane = tid & 63, wv = tid >> 6;
    __shared__ int wtot[4];
    __shared__ int carry_s;
    if (tid == 0) carry_s = 0;
    __syncthreads();

    for (int c0 = 0; c0 < N_TOK * TOPK; c0 += 1024) {
        int i = c0 + tid * 4;
        int4 v = *(const int4*)(tki + i);
        int m0 = (v.x == e), m1 = (v.y == e), m2 = (v.z == e), m3 = (v.w == e);
        int mc = m0 + m1 + m2 + m3;
        int sc = mc;
        #pragma unroll
        for (int off = 1; off < 64; off <<= 1) {
            int o = __shfl_up(sc, off);
            if (lane >= off) sc += o;
        }
        if (lane == 63) wtot[wv] = sc;
        int excl = sc - mc;
        __syncthreads();
        int wbase = 0;
        #pragma unroll
        for (int j = 0; j < 4; ++j) if (j < wv) wbase += wtot[j];
        int tot = wtot[0] + wtot[1] + wtot[2] + wtot[3];
        int pos = carry_s + wbase + excl;
        if (m0) { if (pos < cap) { tlist[(size_t)e*cap+pos] = i;   wlist[(size_t)e*cap+pos] = tkw[i];   } pos++; }
        if (m1) { if (pos < cap) { tlist[(size_t)e*cap+pos] = i+1; wlist[(size_t)e*cap+pos] = tkw[i+1]; } pos++; }
        if (m2) { if (pos < cap) { tlist[(size_t)e*cap+pos] = i+2; wlist[(size_t)e*cap+pos] = tkw[i+2]; } pos++; }
        if (m3) { if (pos < cap) { tlist[(size_t)e*cap+pos] = i+3; wlist[(size_t)e*cap+pos] = tkw[i+3]; } pos++; }
        __syncthreads();
        if (tid == 0) carry_s += tot;
        __syncthreads();
    }
    if (tid == 0) counts[e] = min(carry_s, cap);
    __syncthreads();
    int cnt = min(carry_s, cap);
    int padded = (cnt + 255) & ~255;
    for (int i = cnt + tid; i < padded; i += 256) {
        tlist[(size_t)e*cap + i] = 0;
        wlist[(size_t)e*cap + i] = 0.0f;
    }
}

// ======== tier-3: 256x256, Gray-code 4-phase/K-tile, counted vmcnt (T3+T4+T5) ========
// Phases per K-tile: (k0,mh0)+readB | (k0,mh1) reuse B | (k1,mh1)+readB | (k1,mh0) reuse B.
// Staging of tile t+1 interleaved 2 gll16/phase: B,B,Amh0,Amh1 -> vmcnt {2,2,4,6}, never 0.
#define PADW 264

__global__ __launch_bounds__(512) void k_moe256(
    const short* __restrict__ hb, const short* __restrict__ wb,
    const int* __restrict__ counts, const int* __restrict__ tlist,
    const float* __restrict__ wlist, unsigned short* __restrict__ contrib, int cap)
{
    __shared__ short As[2 * 16384];   // [slot][256 rows][64], chunk pos = c^(row&7)
    __shared__ short Bs[2 * 16384];
    __shared__ int   slots[256];
    __shared__ float wgts[256];

    int bx = blockIdx.x;
    int g  = ((bx >> 6) << 3) | (bx & 7);   // 0..255 = e*4+nt
    int mt = (bx >> 3) & 7;
    int e  = g >> 2;
    int n0 = (g & 3) * 256;
    int cnt = counts[e]; if (cnt > cap) cnt = cap;
    if (mt * 256 >= cnt) return;

    int tid = threadIdx.x, lane = tid & 63, w = tid >> 6;   // w 0..7
    int wm = w >> 2, wn = w & 3;                            // 2m x 4n waves

    if (tid < 256) {
        size_t base = (size_t)e * cap + (size_t)mt * 256 + tid;
        slots[tid] = tlist[base];
        wgts[tid]  = wlist[base];
    }
    __syncthreads();

    // B staging (R12 mapping): load i covers rows (w*4+i)*8..+7, pre-swizzled chunk
    const short* baddr[4];
    #pragma unroll
    for (int i = 0; i < 4; ++i) {
        int row = (w*4 + i)*8 + (lane >> 3);
        int gch = (lane & 7) ^ (row & 7);
        baddr[i] = wb + ((size_t)e << 20) + (size_t)(n0 + row) * DIM + gch*8;
    }
    // A staging remapped by m-half: wave stages groups g=w*2+j within each half-class.
    // rows(mh,g) = mh*64 + g*8 + (g>=8 ? 64 : 0)  (8-row aligned)
    const short* aaddr2[2][2];
    int baseA[2][2];
    #pragma unroll
    for (int mh = 0; mh < 2; ++mh)
        #pragma unroll
        for (int j = 0; j < 2; ++j) {
            int gg = w*2 + j;
            int br = mh*64 + gg*8 + ((gg >= 8) ? 64 : 0);
            baseA[mh][j] = br * 64;                       // LDS short offset
            int r8 = lane >> 3;
            int ch = (lane & 7) ^ r8;
            aaddr2[mh][j] = hb + (size_t)(slots[br + r8] >> 3) * DIM + ch*8;
        }

    floatx4 acc[8][4];   // acc[mh*4+mm][nn]: row wm*128+mh*64+mm*16, col wn*64+nn*16
    #pragma unroll
    for (int i = 0; i < 8; ++i)
        #pragma unroll
        for (int j = 0; j < 4; ++j) acc[i][j] = (floatx4)0.0f;

    // prologue: tile 0 -> slot 0 (B x4, Amh0 x2, Amh1 x2), full drain
    #pragma unroll
    for (int i = 0; i < 4; ++i) gll16(baddr[i], &Bs[(w*4 + i)*512]);
    gll16(aaddr2[0][0], &As[baseA[0][0]]);
    gll16(aaddr2[0][1], &As[baseA[0][1]]);
    gll16(aaddr2[1][0], &As[baseA[1][0]]);
    gll16(aaddr2[1][1], &As[baseA[1][1]]);
    asm volatile("s_waitcnt vmcnt(0)" ::: "memory");
    __builtin_amdgcn_s_barrier();

    short8 bfk[4];   // persists across phase pairs

#define PHASE(KK, MH, RB, NW, ...) do { \
    asm volatile("s_waitcnt vmcnt(" #NW ")" ::: "memory"); \
    __builtin_amdgcn_s_barrier(); \
    short8 af[4]; \
    { \
        int rr = lane & 15; \
        int gch = (KK)*4 + (lane >> 4); \
        if (RB) { \
            _Pragma("unroll") \
            for (int nn = 0; nn < 4; ++nn) { \
                int rowb = wn*64 + nn*16 + rr; \
                bfk[nn] = ds_read128(&Bcur[rowb*64 + ((gch ^ (rowb & 7)) * 8)]); \
            } \
        } \
        _Pragma("unroll") \
        for (int mm = 0; mm < 4; ++mm) { \
            int rowa = wm*128 + (MH)*64 + mm*16 + rr; \
            af[mm] = ds_read128(&Acur[rowa*64 + ((gch ^ (rowa & 7)) * 8)]); \
        } \
    } \
    __VA_ARGS__; \
    asm volatile("s_waitcnt lgkmcnt(0)" ::: "memory"); \
    __builtin_amdgcn_sched_barrier(0); \
    __builtin_amdgcn_s_setprio(1); \
    _Pragma("unroll") \
    for (int mm = 0; mm < 4; ++mm) \
        _Pragma("unroll") \
        for (int nn = 0; nn < 4; ++nn) \
            acc[(MH)*4+mm][nn] = __builtin_amdgcn_mfma_f32_16x16x32_bf16( \
                af[mm], bfk[nn], acc[(MH)*4+mm][nn], 0, 0, 0); \
    __builtin_amdgcn_s_setprio(0); \
} while (0)

    for (int t = 0; t < 15; ++t) {
        const int cs = t & 1;
        const short* Acur = &As[cs*16384];
        const short* Bcur = &Bs[cs*16384];
        short* Anx = &As[(cs^1)*16384];
        short* Bnx = &Bs[(cs^1)*16384];
        const int koff = (t+1)*64;
        PHASE(0,0,1, 2, { gll16(baddr[0]+koff, Bnx + (w*4+0)*512);
                          gll16(baddr[1]+koff, Bnx + (w*4+1)*512); });
        PHASE(0,1,0, 2, { gll16(baddr[2]+koff, Bnx + (w*4+2)*512);
                          gll16(baddr[3]+koff, Bnx + (w*4+3)*512); });
        PHASE(1,1,1, 4, { gll16(aaddr2[0][0]+koff, Anx + baseA[0][0]);
                          gll16(aaddr2[0][1]+koff, Anx + baseA[0][1]); });
        PHASE(1,0,0, 6, { gll16(aaddr2[1][0]+koff, Anx + baseA[1][0]);
                          gll16(aaddr2[1][1]+koff, Anx + baseA[1][1]); });
    }
    {   // tail: tile 15, no staging, drain as consumed
        const short* Acur = &As[16384];
        const short* Bcur = &Bs[16384];
        PHASE(0,0,1, 2, {});
        PHASE(0,1,0, 0, {});
        PHASE(1,1,1, 0, {});
        PHASE(1,0,0, 0, {});
    }
#undef PHASE

    // epilogue: LDS transpose (reuse As) -> 32B-contiguous bf16 stores
    short* pad = As;    // 32*PADW = 8448 shorts <= 32768
    int cgrp = lane >> 4, ccol = lane & 15;
    #pragma unroll
    for (int q8 = 0; q8 < 8; ++q8) {
        int mh = q8 >> 2, mm = q8 & 3;
        __syncthreads();
        #pragma unroll
        for (int r = 0; r < 4; ++r) {
            int sub = cgrp*4 + r;
            float wgt = wgts[wm*128 + mh*64 + mm*16 + sub];
            #pragma unroll
            for (int nn = 0; nn < 4; ++nn)
                pad[(wm*16 + sub)*PADW + wn*64 + nn*16 + ccol] =
                    f2bf(wgt * acc[q8][nn][r]);
        }
        __syncthreads();
        int prow = tid >> 4, piece = tid & 15;
        int wm2 = prow >> 4, sub = prow & 15;
        int grow = wm2*128 + mh*64 + mm*16 + sub;
        if (wgts[grow] != 0.0f) {
            size_t base = (size_t)slots[grow] * DIM + n0 + piece*16;
            uint4 v0 = *(const uint4*)&pad[prow*PADW + piece*16];
            uint4 v1 = *(const uint4*)&pad[prow*PADW + piece*16 + 8];
            *(uint4*)&contrib[base]     = v0;
            *(uint4*)&contrib[base + 8] = v1;
        }
    }
}

// ---------------- fallback gathered GEMM (tiers 0-1, atomics) ----------------
#define BMo 256
#define BNo 128
#define LDT 72
template<bool AB>
__global__ __launch_bounds__(512) void k_moe(
    const float* __restrict__ h, const short* __restrict__ hb,
    const float* __restrict__ ew,
    const int* __restrict__ counts, const int* __restrict__ tlist,
    const float* __restrict__ wlist, float* __restrict__ out, int cap)
{
    __shared__ short As[BMo * LDT];
    __shared__ short Bs[BNo * LDT];
    __shared__ int   slots[BMo];
    __shared__ float wgts[BMo];

    int e  = blockIdx.x >> 3;
    int n0 = (blockIdx.x & 7) * BNo;
    int cnt = counts[e];
    if (cnt > cap) cnt = cap;
    if (cnt == 0) return;
    int ntiles = (cnt + BMo - 1) / BMo;

    int tid  = threadIdx.x;
    int lane = tid & 63;
    int wv = tid >> 6;
    int wm = wv >> 1;
    int wn = wv & 1;

    int arow = tid >> 1;
    int acol = (tid & 1) * 32;
    int brow = tid >> 2;
    int bcol = (tid & 3) * 16;
    const float* wbasef = ew + ((size_t)e << 20) + (size_t)(n0 + brow) * DIM + bcol;

    float4 raf[8];
    uint4  rab[4];
    float4 rbf[4];

    for (int mtt = 0; mtt < ntiles; ++mtt) {
        __syncthreads();
        if (tid < BMo) {
            size_t base = (size_t)e * cap + (size_t)mtt * BMo + tid;
            slots[tid] = tlist[base];
            wgts[tid]  = wlist[base];
        }
        __syncthreads();

        floatx4 acc[4][4];
        #pragma unroll
        for (int i = 0; i < 4; ++i)
            #pragma unroll
            for (int j = 0; j < 4; ++j) acc[i][j] = (floatx4)0.0f;

        size_t trow = (size_t)(slots[arow] >> 3);
        const float* hrowf = h  + trow * DIM + acol;
        const short* hrowb = hb + trow * DIM + acol;

        if constexpr (AB) {
            #pragma unroll
            for (int j = 0; j < 4; ++j) rab[j] = *(const uint4*)(hrowb + j*8);
        } else {
            #pragma unroll
            for (int j = 0; j < 4; ++j) {
                raf[2*j]   = *(const float4*)(hrowf + j*8);
                raf[2*j+1] = *(const float4*)(hrowf + j*8 + 4);
            }
        }
        #pragma unroll
        for (int j = 0; j < 4; ++j) rbf[j] = *(const float4*)(wbasef + j*4);

        for (int k0 = 0; k0 < DIM; k0 += 64) {
            if constexpr (AB) {
                #pragma unroll
                for (int j = 0; j < 4; ++j)
                    *(uint4*)&As[arow*LDT + acol + j*8] = rab[j];
            } else {
                #pragma unroll
                for (int j = 0; j < 4; ++j)
                    *(short8*)&As[arow*LDT + acol + j*8] = pack8(raf[2*j], raf[2*j+1]);
            }
            #pragma unroll
            for (int j = 0; j < 2; ++j)
                *(short8*)&Bs[brow*LDT + bcol + j*8] = pack8(rbf[2*j], rbf[2*j+1]);
            __syncthreads();

            int kn = k0 + 64;
            if (kn < DIM) {
                if constexpr (AB) {
                    #pragma unroll
                    for (int j = 0; j < 4; ++j) rab[j] = *(const uint4*)(hrowb + kn + j*8);
                } else {
                    #pragma unroll
                    for (int j = 0; j < 4; ++j) {
                        raf[2*j]   = *(const float4*)(hrowf + kn + j*8);
                        raf[2*j+1] = *(const float4*)(hrowf + kn + j*8 + 4);
                    }
                }
                #pragma unroll
                for (int j = 0; j < 4; ++j) rbf[j] = *(const float4*)(wbasef + kn + j*4);
            }

            #pragma unroll
            for (int s = 0; s < 2; ++s) {
                int ko = s*32 + (lane >> 4) * 8;
                int rr = lane & 15;
                short8 af[4], bfr[4];
                #pragma unroll
                for (int mm = 0; mm < 4; ++mm)
                    af[mm] = *(const short8*)&As[(wm*64 + mm*16 + rr)*LDT + ko];
                #pragma unroll
                for (int nn = 0; nn < 4; ++nn)
                    bfr[nn] = *(const short8*)&Bs[(wn*64 + nn*16 + rr)*LDT + ko];
                #pragma unroll
                for (int mm = 0; mm < 4; ++mm)
                    #pragma unroll
                    for (int nn = 0; nn < 4; ++nn)
                        acc[mm][nn] = __builtin_amdgcn_mfma_f32_16x16x32_bf16(
                            af[mm], bfr[nn], acc[mm][nn], 0, 0, 0);
            }
            __syncthreads();
        }

        int cgrp = lane >> 4;
        int ccol = lane & 15;
        #pragma unroll
        for (int mm = 0; mm < 4; ++mm) {
            #pragma unroll
            for (int r = 0; r < 4; ++r) {
                int row = wm*64 + mm*16 + cgrp*4 + r;
                float wgt = wgts[row];
                if (wgt != 0.0f) {
                    size_t tok = (size_t)(slots[row] >> 3);
                    #pragma unroll
                    for (int nn = 0; nn < 4; ++nn) {
                        int col = n0 + wn*64 + nn*16 + ccol;
                        atomicAdd(&out[tok * DIM + col], wgt * acc[mm][nn][r]);
                    }
                }
            }
        }
    }
}

// ---------------- gather: out[t] = sum_k contrib[t*8+k] (16B loads) ----------------
__global__ __launch_bounds__(128) void k_gather(
    const unsigned short* __restrict__ contrib, float* __restrict__ out) {
    int t = blockIdx.x;
    int c = threadIdx.x * 8;
    float s[8] = {0,0,0,0,0,0,0,0};
    #pragma unroll
    for (int k = 0; k < TOPK; ++k) {
        uint4 v = *(const uint4*)(contrib + ((size_t)t * TOPK + k) * DIM + c);
        s[0] += bf2f(v.x & 0xffff); s[1] += bf2f(v.x >> 16);
        s[2] += bf2f(v.y & 0xffff); s[3] += bf2f(v.y >> 16);
        s[4] += bf2f(v.z & 0xffff); s[5] += bf2f(v.z >> 16);
        s[6] += bf2f(v.w & 0xffff); s[7] += bf2f(v.w >> 16);
    }
    float4 o0 = {s[0], s[1], s[2], s[3]};
    float4 o1 = {s[4], s[5], s[6], s[7]};
    *(float4*)(out + (size_t)t * DIM + c)     = o0;
    *(float4*)(out + (size_t)t * DIM + c + 4) = o1;
}

extern "C" void kernel_launch(void* const* d_in, const int* in_sizes, int n_in,
                              void* d_out, int out_size, void* d_ws, size_t ws_size,
                              hipStream_t stream) {
    const float* h  = (const float*)d_in[0];
    const float* gw = (const float*)d_in[1];
    const float* ew = (const float*)d_in[2];
    float* out    = (float*)d_out;
    float* logits = out + (size_t)N_TOK * DIM;

    const size_t SZ_TK   = (size_t)N_TOK * TOPK * 4;
    const size_t SZ_HB   = (size_t)N_TOK * DIM * 2;
    const size_t SZ_WB   = (size_t)NEXP * DIM * DIM * 2;
    const size_t SZ_CT   = (size_t)N_TOK * TOPK * DIM * 2;
    const size_t SZ_LIST = (size_t)CAPF * NEXP * 4;

    size_t need_base = 4096 + 2*SZ_LIST + 2*SZ_TK + SZ_HB;
    size_t need_t3   = need_base + SZ_WB + SZ_CT;

    int tier;
    long cap = CAPF;
    if      (ws_size >= need_t3)   tier = 3;
    else if (ws_size >= need_base) tier = 1;
    else {
        tier = 0;
        size_t avail = (ws_size > 4096 + 2*SZ_TK) ? ws_size - 4096 - 2*SZ_TK : 0;
        cap = (long)(avail / ((size_t)NEXP * 8));
        cap &= ~255L;
        if (cap > N_TOK) cap = N_TOK;
    }

    char* ws = (char*)d_ws;
    size_t off = 0;
    int*   counts = (int*)(ws + off);  off += 4096;
    int*   tlist  = (int*)(ws + off);  off += (size_t)cap * NEXP * 4;
    float* wlist  = (float*)(ws + off); off += (size_t)cap * NEXP * 4;
    int*   tki    = (int*)(ws + off);  off += SZ_TK;
    float* tkw    = (float*)(ws + off); off += SZ_TK;
    short* hb     = (short*)(ws + off); if (tier >= 1) off += SZ_HB;
    short* wbuf   = (short*)(ws + off); if (tier >= 3) off += SZ_WB;
    unsigned short* contrib = (unsigned short*)(ws + off);

    if (cap >= 256 && tier < 3)
        hipMemsetAsync(out, 0, (size_t)N_TOK*DIM*4, stream);

    unsigned prep_blocks = 256 + (tier >= 3 ? (unsigned)((size_t)NEXP*DIM*DIM/(256*8)) : 0);
    k_prep<<<dim3(prep_blocks), 256, 0, stream>>>(
        h, gw, logits, (tier >= 1 && cap >= 256) ? hb : (short*)nullptr, ew, wbuf,
        tki, tkw);

    if (cap < 256) return;

    k_topk2<<<dim3(NEXP), 256, 0, stream>>>(tki, tkw, counts, tlist, wlist, (int)cap);

    if (tier == 3) {
        k_moe256<<<dim3(32 * 64), 512, 0, stream>>>(
            hb, wbuf, counts, tlist, wlist, contrib, (int)cap);
        k_gather<<<dim3(N_TOK), 128, 0, stream>>>(contrib, out);
    } else if (tier == 1) {
        k_moe<true><<<dim3(NEXP*8), 512, 0, stream>>>(
            h, hb, ew, counts, tlist, wlist, out, (int)cap);
    } else {
        k_moe<false><<<dim3(NEXP*8), 512, 0, stream>>>(
            h, hb, ew, counts, tlist, wlist, out, (int)cap);
    }
}

// Round 18
// 398.704 us; speedup vs baseline: 1.0873x; 1.0223x over previous
//
#include <hip/hip_runtime.h>
#include <hip/hip_bf16.h>
#include <math.h>

#define N_TOK 8192
#define DIM   1024
#define NEXP  64
#define TOPK  8
#define CAPF  2048     // per-expert list capacity (mean 1024, ~34 sigma headroom)

typedef __attribute__((ext_vector_type(8))) short short8;
typedef __attribute__((ext_vector_type(4))) float floatx4;
typedef unsigned int u32;

static __device__ __forceinline__ short f2bf(float f) {
    union { float f; unsigned u; } c; c.f = f;
    unsigned r = c.u + 0x7FFF + ((c.u >> 16) & 1);   // RNE
    return (short)(r >> 16);
}
static __device__ __forceinline__ float bf2f(unsigned s) {   // low 16 bits = bf16
    union { unsigned u; float f; } c; c.u = s << 16;
    return c.f;
}
static __device__ __forceinline__ short8 pack8(float4 a, float4 b) {
    short8 o;
    o[0]=f2bf(a.x); o[1]=f2bf(a.y); o[2]=f2bf(a.z); o[3]=f2bf(a.w);
    o[4]=f2bf(b.x); o[5]=f2bf(b.y); o[6]=f2bf(b.z); o[7]=f2bf(b.w);
    return o;
}
// async global->LDS, 16B/lane; lds ptr wave-uniform (HW: base + lane*16)
static __device__ __forceinline__ void gll16(const short* g, short* l) {
    __builtin_amdgcn_global_load_lds(
        (const __attribute__((address_space(1))) u32*)(const void*)g,
        (__attribute__((address_space(3))) u32*)(void*)l, 16, 0, 0);
}
// inline-asm LDS b128 read: opaque to alias analysis (no auto vmcnt drains)
static __device__ __forceinline__ short8 ds_read128(const short* p) {
    short8 v;
    asm volatile("ds_read_b128 %0, %1"
                 : "=v"(v)
                 : "v"((const __attribute__((address_space(3))) short*)p));
    return v;
}

// ---- fused prep: router + h->bf16 + inline top-8 (blocks 0..255) | W->bf16 (rest) ----
__global__ __launch_bounds__(256) void k_prep(
    const float* __restrict__ h, const float* __restrict__ gw,
    float* __restrict__ logits, short* __restrict__ hb,
    const float* __restrict__ ew, short* __restrict__ wb,
    int* __restrict__ tki, float* __restrict__ tkw)
{
    __shared__ float hs[32 * 68];
    __shared__ float gs[64 * 68];
    int bx = blockIdx.x;
    int tid = threadIdx.x;

    if (bx >= 256) {   // W convert chunk (independent, BW-bound)
        size_t i = ((size_t)(bx - 256) * 256 + tid) * 8;
        float4 f0 = *(const float4*)(ew + i);
        float4 f1 = *(const float4*)(ew + i + 4);
        *(short8*)(wb + i) = pack8(f0, f1);
        return;
    }

    int t0 = bx * 32;
    int tm = tid & 15;
    int en = tid >> 4;
    float acc[2][4] = {{0.f,0.f,0.f,0.f},{0.f,0.f,0.f,0.f}};

    for (int k0 = 0; k0 < DIM; k0 += 64) {
        {
            int row = tid >> 3, seg = (tid & 7) * 8;
            const float* src = h + (size_t)(t0 + row) * DIM + k0 + seg;
            float4 f0 = *(const float4*)src;
            float4 f1 = *(const float4*)(src + 4);
            *(float4*)&hs[row*68 + seg]     = f0;
            *(float4*)&hs[row*68 + seg + 4] = f1;
            if (hb)
                *(short8*)(hb + (size_t)(t0 + row) * DIM + k0 + seg) = pack8(f0, f1);
        }
        {
            int row = tid >> 2, seg = (tid & 3) * 16;
            const float* src = gw + (size_t)row * DIM + k0 + seg;
            float4* dst = (float4*)&gs[row*68 + seg];
            #pragma unroll
            for (int j = 0; j < 4; ++j) dst[j] = *(const float4*)(src + j*4);
        }
        __syncthreads();
        #pragma unroll
        for (int k4 = 0; k4 < 16; ++k4) {
            float4 h0 = *(const float4*)&hs[tm*68 + k4*4];
            float4 h1 = *(const float4*)&hs[(tm+16)*68 + k4*4];
            #pragma unroll
            for (int j = 0; j < 4; ++j) {
                float4 g = *(const float4*)&gs[(en + 16*j)*68 + k4*4];
                acc[0][j] += h0.x*g.x + h0.y*g.y + h0.z*g.z + h0.w*g.w;
                acc[1][j] += h1.x*g.x + h1.y*g.y + h1.z*g.z + h1.w*g.w;
            }
        }
        __syncthreads();
    }
    #pragma unroll
    for (int r = 0; r < 2; ++r)
        #pragma unroll
        for (int j = 0; j < 4; ++j)
            logits[(size_t)(t0 + tm + 16*r) * NEXP + en + 16*j] = acc[r][j];

    // ---- fused top-8: stage logit rows in LDS, wave-per-token reduce ----
    float* sl = hs;    // reuse as [32][65]
    #pragma unroll
    for (int r = 0; r < 2; ++r)
        #pragma unroll
        for (int j = 0; j < 4; ++j)
            sl[(tm + 16*r)*65 + en + 16*j] = acc[r][j];
    __syncthreads();

    int wv = tid >> 6, lane = tid & 63;
    for (int ti = 0; ti < 8; ++ti) {
        int tok = wv*8 + ti;
        float x = sl[tok*65 + lane];
        float m = x;
        #pragma unroll
        for (int off = 32; off; off >>= 1) m = fmaxf(m, __shfl_xor(m, off));
        float p = expf(x - m);
        float s = p;
        #pragma unroll
        for (int off = 32; off; off >>= 1) s += __shfl_xor(s, off);
        float cur = p / s;
        for (int k = 0; k < TOPK; ++k) {
            float v = cur; int idx = lane;
            #pragma unroll
            for (int off = 32; off; off >>= 1) {
                float ov = __shfl_xor(v, off);
                int   oi = __shfl_xor(idx, off);
                if (ov > v || (ov == v && oi < idx)) { v = ov; idx = oi; }
            }
            if (lane == idx) cur = -1.0f;
            if (lane == 0) {
                tki[(size_t)(t0 + tok) * TOPK + k] = idx;
                tkw[(size_t)(t0 + tok) * TOPK + k] = v;
            }
        }
    }
}

// ---- compaction into per-expert lists (order-free: LDS-atomic reservation, no
// in-loop barriers; list permutation does not affect out — each slot's GEMM row
// result is independent of its tile's other rows) ----
__global__ void k_topk2(const int* __restrict__ tki, const float* __restrict__ tkw,
                        int* __restrict__ counts, int* __restrict__ tlist,
                        float* __restrict__ wlist, int cap) {
    int e = blockIdx.x, tid = threadIdx.x, lane = tid & 63;
    __shared__ int cnt_s;
    if (tid == 0) cnt_s = 0;
    __syncthreads();

    for (int c0 = 0; c0 < N_TOK * TOPK; c0 += 1024) {
        int i = c0 + tid * 4;
        int4 v = *(const int4*)(tki + i);
        int m0 = (v.x == e), m1 = (v.y == e), m2 = (v.z == e), m3 = (v.w == e);
        int mc = m0 + m1 + m2 + m3;
        int sc = mc;                         // inclusive wave scan
        #pragma unroll
        for (int off = 1; off < 64; off <<= 1) {
            int o = __shfl_up(sc, off);
            if (lane >= off) sc += o;
        }
        int wbase = 0;
        if (lane == 63 && sc > 0) wbase = atomicAdd(&cnt_s, sc);
        wbase = __shfl(wbase, 63);
        int pos = wbase + sc - mc;
        if (m0) { if (pos < cap) { tlist[(size_t)e*cap+pos] = i;   wlist[(size_t)e*cap+pos] = tkw[i];   } pos++; }
        if (m1) { if (pos < cap) { tlist[(size_t)e*cap+pos] = i+1; wlist[(size_t)e*cap+pos] = tkw[i+1]; } pos++; }
        if (m2) { if (pos < cap) { tlist[(size_t)e*cap+pos] = i+2; wlist[(size_t)e*cap+pos] = tkw[i+2]; } pos++; }
        if (m3) { if (pos < cap) { tlist[(size_t)e*cap+pos] = i+3; wlist[(size_t)e*cap+pos] = tkw[i+3]; } pos++; }
    }
    __syncthreads();
    int cnt = min(cnt_s, cap);
    if (tid == 0) counts[e] = cnt;
    // zero the pad slots up to the next 256 multiple (moe reads exactly this range)
    int padded = (cnt + 255) & ~255;
    for (int i = cnt + tid; i < padded; i += 256) {
        tlist[(size_t)e*cap + i] = 0;
        wlist[(size_t)e*cap + i] = 0.0f;
    }
}

// ======== tier-3: 256x256, Gray-code 4-phase/K-tile, counted vmcnt (T3+T4+T5) ========
// Phases per K-tile: (k0,mh0)+readB | (k0,mh1) reuse B | (k1,mh1)+readB | (k1,mh0) reuse B.
// Staging of tile t+1 interleaved 2 gll16/phase: B,B,Amh0,Amh1 -> vmcnt {2,2,4,6}, never 0.
#define PADW 264

__global__ __launch_bounds__(512) void k_moe256(
    const short* __restrict__ hb, const short* __restrict__ wb,
    const int* __restrict__ counts, const int* __restrict__ tlist,
    const float* __restrict__ wlist, unsigned short* __restrict__ contrib, int cap)
{
    __shared__ short As[2 * 16384];   // [slot][256 rows][64], chunk pos = c^(row&7)
    __shared__ short Bs[2 * 16384];
    __shared__ int   slots[256];
    __shared__ float wgts[256];

    int bx = blockIdx.x;
    int g  = ((bx >> 6) << 3) | (bx & 7);   // 0..255 = e*4+nt
    int mt = (bx >> 3) & 7;
    int e  = g >> 2;
    int n0 = (g & 3) * 256;
    int cnt = counts[e]; if (cnt > cap) cnt = cap;
    if (mt * 256 >= cnt) return;

    int tid = threadIdx.x, lane = tid & 63, w = tid >> 6;   // w 0..7
    int wm = w >> 2, wn = w & 3;                            // 2m x 4n waves

    if (tid < 256) {
        size_t base = (size_t)e * cap + (size_t)mt * 256 + tid;
        slots[tid] = tlist[base];
        wgts[tid]  = wlist[base];
    }
    __syncthreads();

    // B staging (R12 mapping): load i covers rows (w*4+i)*8..+7, pre-swizzled chunk
    const short* baddr[4];
    #pragma unroll
    for (int i = 0; i < 4; ++i) {
        int row = (w*4 + i)*8 + (lane >> 3);
        int gch = (lane & 7) ^ (row & 7);
        baddr[i] = wb + ((size_t)e << 20) + (size_t)(n0 + row) * DIM + gch*8;
    }
    // A staging remapped by m-half: wave stages groups g=w*2+j within each half-class.
    // rows(mh,g) = mh*64 + g*8 + (g>=8 ? 64 : 0)  (8-row aligned)
    const short* aaddr2[2][2];
    int baseA[2][2];
    #pragma unroll
    for (int mh = 0; mh < 2; ++mh)
        #pragma unroll
        for (int j = 0; j < 2; ++j) {
            int gg = w*2 + j;
            int br = mh*64 + gg*8 + ((gg >= 8) ? 64 : 0);
            baseA[mh][j] = br * 64;                       // LDS short offset
            int r8 = lane >> 3;
            int ch = (lane & 7) ^ r8;
            aaddr2[mh][j] = hb + (size_t)(slots[br + r8] >> 3) * DIM + ch*8;
        }

    floatx4 acc[8][4];   // acc[mh*4+mm][nn]: row wm*128+mh*64+mm*16, col wn*64+nn*16
    #pragma unroll
    for (int i = 0; i < 8; ++i)
        #pragma unroll
        for (int j = 0; j < 4; ++j) acc[i][j] = (floatx4)0.0f;

    // prologue: tile 0 -> slot 0 (B x4, Amh0 x2, Amh1 x2), full drain
    #pragma unroll
    for (int i = 0; i < 4; ++i) gll16(baddr[i], &Bs[(w*4 + i)*512]);
    gll16(aaddr2[0][0], &As[baseA[0][0]]);
    gll16(aaddr2[0][1], &As[baseA[0][1]]);
    gll16(aaddr2[1][0], &As[baseA[1][0]]);
    gll16(aaddr2[1][1], &As[baseA[1][1]]);
    asm volatile("s_waitcnt vmcnt(0)" ::: "memory");
    __builtin_amdgcn_s_barrier();

    short8 bfk[4];   // persists across phase pairs

#define PHASE(KK, MH, RB, NW, ...) do { \
    asm volatile("s_waitcnt vmcnt(" #NW ")" ::: "memory"); \
    __builtin_amdgcn_s_barrier(); \
    short8 af[4]; \
    { \
        int rr = lane & 15; \
        int gch = (KK)*4 + (lane >> 4); \
        if (RB) { \
            _Pragma("unroll") \
            for (int nn = 0; nn < 4; ++nn) { \
                int rowb = wn*64 + nn*16 + rr; \
                bfk[nn] = ds_read128(&Bcur[rowb*64 + ((gch ^ (rowb & 7)) * 8)]); \
            } \
        } \
        _Pragma("unroll") \
        for (int mm = 0; mm < 4; ++mm) { \
            int rowa = wm*128 + (MH)*64 + mm*16 + rr; \
            af[mm] = ds_read128(&Acur[rowa*64 + ((gch ^ (rowa & 7)) * 8)]); \
        } \
    } \
    __VA_ARGS__; \
    asm volatile("s_waitcnt lgkmcnt(0)" ::: "memory"); \
    __builtin_amdgcn_sched_barrier(0); \
    __builtin_amdgcn_s_setprio(1); \
    _Pragma("unroll") \
    for (int mm = 0; mm < 4; ++mm) \
        _Pragma("unroll") \
        for (int nn = 0; nn < 4; ++nn) \
            acc[(MH)*4+mm][nn] = __builtin_amdgcn_mfma_f32_16x16x32_bf16( \
                af[mm], bfk[nn], acc[(MH)*4+mm][nn], 0, 0, 0); \
    __builtin_amdgcn_s_setprio(0); \
} while (0)

    for (int t = 0; t < 15; ++t) {
        const int cs = t & 1;
        const short* Acur = &As[cs*16384];
        const short* Bcur = &Bs[cs*16384];
        short* Anx = &As[(cs^1)*16384];
        short* Bnx = &Bs[(cs^1)*16384];
        const int koff = (t+1)*64;
        PHASE(0,0,1, 2, { gll16(baddr[0]+koff, Bnx + (w*4+0)*512);
                          gll16(baddr[1]+koff, Bnx + (w*4+1)*512); });
        PHASE(0,1,0, 2, { gll16(baddr[2]+koff, Bnx + (w*4+2)*512);
                          gll16(baddr[3]+koff, Bnx + (w*4+3)*512); });
        PHASE(1,1,1, 4, { gll16(aaddr2[0][0]+koff, Anx + baseA[0][0]);
                          gll16(aaddr2[0][1]+koff, Anx + baseA[0][1]); });
        PHASE(1,0,0, 6, { gll16(aaddr2[1][0]+koff, Anx + baseA[1][0]);
                          gll16(aaddr2[1][1]+koff, Anx + baseA[1][1]); });
    }
    {   // tail: tile 15, no staging, drain as consumed
        const short* Acur = &As[16384];
        const short* Bcur = &Bs[16384];
        PHASE(0,0,1, 2, {});
        PHASE(0,1,0, 0, {});
        PHASE(1,1,1, 0, {});
        PHASE(1,0,0, 0, {});
    }
#undef PHASE

    // epilogue: LDS transpose (reuse As) -> 32B-contiguous bf16 stores
    short* pad = As;    // 32*PADW = 8448 shorts <= 32768
    int cgrp = lane >> 4, ccol = lane & 15;
    #pragma unroll
    for (int q8 = 0; q8 < 8; ++q8) {
        int mh = q8 >> 2, mm = q8 & 3;
        __syncthreads();
        #pragma unroll
        for (int r = 0; r < 4; ++r) {
            int sub = cgrp*4 + r;
            float wgt = wgts[wm*128 + mh*64 + mm*16 + sub];
            #pragma unroll
            for (int nn = 0; nn < 4; ++nn)
                pad[(wm*16 + sub)*PADW + wn*64 + nn*16 + ccol] =
                    f2bf(wgt * acc[q8][nn][r]);
        }
        __syncthreads();
        int prow = tid >> 4, piece = tid & 15;
        int wm2 = prow >> 4, sub = prow & 15;
        int grow = wm2*128 + mh*64 + mm*16 + sub;
        if (wgts[grow] != 0.0f) {
            size_t base = (size_t)slots[grow] * DIM + n0 + piece*16;
            uint4 v0 = *(const uint4*)&pad[prow*PADW + piece*16];
            uint4 v1 = *(const uint4*)&pad[prow*PADW + piece*16 + 8];
            *(uint4*)&contrib[base]     = v0;
            *(uint4*)&contrib[base + 8] = v1;
        }
    }
}

// ---------------- fallback gathered GEMM (tiers 0-1, atomics) ----------------
#define BMo 256
#define BNo 128
#define LDT 72
template<bool AB>
__global__ __launch_bounds__(512) void k_moe(
    const float* __restrict__ h, const short* __restrict__ hb,
    const float* __restrict__ ew,
    const int* __restrict__ counts, const int* __restrict__ tlist,
    const float* __restrict__ wlist, float* __restrict__ out, int cap)
{
    __shared__ short As[BMo * LDT];
    __shared__ short Bs[BNo * LDT];
    __shared__ int   slots[BMo];
    __shared__ float wgts[BMo];

    int e  = blockIdx.x >> 3;
    int n0 = (blockIdx.x & 7) * BNo;
    int cnt = counts[e];
    if (cnt > cap) cnt = cap;
    if (cnt == 0) return;
    int ntiles = (cnt + BMo - 1) / BMo;

    int tid  = threadIdx.x;
    int lane = tid & 63;
    int wv = tid >> 6;
    int wm = wv >> 1;
    int wn = wv & 1;

    int arow = tid >> 1;
    int acol = (tid & 1) * 32;
    int brow = tid >> 2;
    int bcol = (tid & 3) * 16;
    const float* wbasef = ew + ((size_t)e << 20) + (size_t)(n0 + brow) * DIM + bcol;

    float4 raf[8];
    uint4  rab[4];
    float4 rbf[4];

    for (int mtt = 0; mtt < ntiles; ++mtt) {
        __syncthreads();
        if (tid < BMo) {
            size_t base = (size_t)e * cap + (size_t)mtt * BMo + tid;
            slots[tid] = tlist[base];
            wgts[tid]  = wlist[base];
        }
        __syncthreads();

        floatx4 acc[4][4];
        #pragma unroll
        for (int i = 0; i < 4; ++i)
            #pragma unroll
            for (int j = 0; j < 4; ++j) acc[i][j] = (floatx4)0.0f;

        size_t trow = (size_t)(slots[arow] >> 3);
        const float* hrowf = h  + trow * DIM + acol;
        const short* hrowb = hb + trow * DIM + acol;

        if constexpr (AB) {
            #pragma unroll
            for (int j = 0; j < 4; ++j) rab[j] = *(const uint4*)(hrowb + j*8);
        } else {
            #pragma unroll
            for (int j = 0; j < 4; ++j) {
                raf[2*j]   = *(const float4*)(hrowf + j*8);
                raf[2*j+1] = *(const float4*)(hrowf + j*8 + 4);
            }
        }
        #pragma unroll
        for (int j = 0; j < 4; ++j) rbf[j] = *(const float4*)(wbasef + j*4);

        for (int k0 = 0; k0 < DIM; k0 += 64) {
            if constexpr (AB) {
                #pragma unroll
                for (int j = 0; j < 4; ++j)
                    *(uint4*)&As[arow*LDT + acol + j*8] = rab[j];
            } else {
                #pragma unroll
                for (int j = 0; j < 4; ++j)
                    *(short8*)&As[arow*LDT + acol + j*8] = pack8(raf[2*j], raf[2*j+1]);
            }
            #pragma unroll
            for (int j = 0; j < 2; ++j)
                *(short8*)&Bs[brow*LDT + bcol + j*8] = pack8(rbf[2*j], rbf[2*j+1]);
            __syncthreads();

            int kn = k0 + 64;
            if (kn < DIM) {
                if constexpr (AB) {
                    #pragma unroll
                    for (int j = 0; j < 4; ++j) rab[j] = *(const uint4*)(hrowb + kn + j*8);
                } else {
                    #pragma unroll
                    for (int j = 0; j < 4; ++j) {
                        raf[2*j]   = *(const float4*)(hrowf + kn + j*8);
                        raf[2*j+1] = *(const float4*)(hrowf + kn + j*8 + 4);
                    }
                }
                #pragma unroll
                for (int j = 0; j < 4; ++j) rbf[j] = *(const float4*)(wbasef + kn + j*4);
            }

            #pragma unroll
            for (int s = 0; s < 2; ++s) {
                int ko = s*32 + (lane >> 4) * 8;
                int rr = lane & 15;
                short8 af[4], bfr[4];
                #pragma unroll
                for (int mm = 0; mm < 4; ++mm)
                    af[mm] = *(const short8*)&As[(wm*64 + mm*16 + rr)*LDT + ko];
                #pragma unroll
                for (int nn = 0; nn < 4; ++nn)
                    bfr[nn] = *(const short8*)&Bs[(wn*64 + nn*16 + rr)*LDT + ko];
                #pragma unroll
                for (int mm = 0; mm < 4; ++mm)
                    #pragma unroll
                    for (int nn = 0; nn < 4; ++nn)
                        acc[mm][nn] = __builtin_amdgcn_mfma_f32_16x16x32_bf16(
                            af[mm], bfr[nn], acc[mm][nn], 0, 0, 0);
            }
            __syncthreads();
        }

        int cgrp = lane >> 4;
        int ccol = lane & 15;
        #pragma unroll
        for (int mm = 0; mm < 4; ++mm) {
            #pragma unroll
            for (int r = 0; r < 4; ++r) {
                int row = wm*64 + mm*16 + cgrp*4 + r;
                float wgt = wgts[row];
                if (wgt != 0.0f) {
                    size_t tok = (size_t)(slots[row] >> 3);
                    #pragma unroll
                    for (int nn = 0; nn < 4; ++nn) {
                        int col = n0 + wn*64 + nn*16 + ccol;
                        atomicAdd(&out[tok * DIM + col], wgt * acc[mm][nn][r]);
                    }
                }
            }
        }
    }
}

// ---------------- gather: out[t] = sum_k contrib[t*8+k] (16B loads) ----------------
__global__ __launch_bounds__(128) void k_gather(
    const unsigned short* __restrict__ contrib, float* __restrict__ out) {
    int t = blockIdx.x;
    int c = threadIdx.x * 8;
    float s[8] = {0,0,0,0,0,0,0,0};
    #pragma unroll
    for (int k = 0; k < TOPK; ++k) {
        uint4 v = *(const uint4*)(contrib + ((size_t)t * TOPK + k) * DIM + c);
        s[0] += bf2f(v.x & 0xffff); s[1] += bf2f(v.x >> 16);
        s[2] += bf2f(v.y & 0xffff); s[3] += bf2f(v.y >> 16);
        s[4] += bf2f(v.z & 0xffff); s[5] += bf2f(v.z >> 16);
        s[6] += bf2f(v.w & 0xffff); s[7] += bf2f(v.w >> 16);
    }
    float4 o0 = {s[0], s[1], s[2], s[3]};
    float4 o1 = {s[4], s[5], s[6], s[7]};
    *(float4*)(out + (size_t)t * DIM + c)     = o0;
    *(float4*)(out + (size_t)t * DIM + c + 4) = o1;
}

extern "C" void kernel_launch(void* const* d_in, const int* in_sizes, int n_in,
                              void* d_out, int out_size, void* d_ws, size_t ws_size,
                              hipStream_t stream) {
    const float* h  = (const float*)d_in[0];
    const float* gw = (const float*)d_in[1];
    const float* ew = (const float*)d_in[2];
    float* out    = (float*)d_out;
    float* logits = out + (size_t)N_TOK * DIM;

    const size_t SZ_TK   = (size_t)N_TOK * TOPK * 4;
    const size_t SZ_HB   = (size_t)N_TOK * DIM * 2;
    const size_t SZ_WB   = (size_t)NEXP * DIM * DIM * 2;
    const size_t SZ_CT   = (size_t)N_TOK * TOPK * DIM * 2;
    const size_t SZ_LIST = (size_t)CAPF * NEXP * 4;

    size_t need_base = 4096 + 2*SZ_LIST + 2*SZ_TK + SZ_HB;
    size_t need_t3   = need_base + SZ_WB + SZ_CT;

    int tier;
    long cap = CAPF;
    if      (ws_size >= need_t3)   tier = 3;
    else if (ws_size >= need_base) tier = 1;
    else {
        tier = 0;
        size_t avail = (ws_size > 4096 + 2*SZ_TK) ? ws_size - 4096 - 2*SZ_TK : 0;
        cap = (long)(avail / ((size_t)NEXP * 8));
        cap &= ~255L;
        if (cap > N_TOK) cap = N_TOK;
    }

    char* ws = (char*)d_ws;
    size_t off = 0;
    int*   counts = (int*)(ws + off);  off += 4096;
    int*   tlist  = (int*)(ws + off);  off += (size_t)cap * NEXP * 4;
    float* wlist  = (float*)(ws + off); off += (size_t)cap * NEXP * 4;
    int*   tki    = (int*)(ws + off);  off += SZ_TK;
    float* tkw    = (float*)(ws + off); off += SZ_TK;
    short* hb     = (short*)(ws + off); if (tier >= 1) off += SZ_HB;
    short* wbuf   = (short*)(ws + off); if (tier >= 3) off += SZ_WB;
    unsigned short* contrib = (unsigned short*)(ws + off);

    if (cap >= 256 && tier < 3)
        hipMemsetAsync(out, 0, (size_t)N_TOK*DIM*4, stream);

    unsigned prep_blocks = 256 + (tier >= 3 ? (unsigned)((size_t)NEXP*DIM*DIM/(256*8)) : 0);
    k_prep<<<dim3(prep_blocks), 256, 0, stream>>>(
        h, gw, logits, (tier >= 1 && cap >= 256) ? hb : (short*)nullptr, ew, wbuf,
        tki, tkw);

    if (cap < 256) return;

    k_topk2<<<dim3(NEXP), 256, 0, stream>>>(tki, tkw, counts, tlist, wlist, (int)cap);

    if (tier == 3) {
        k_moe256<<<dim3(32 * 64), 512, 0, stream>>>(
            hb, wbuf, counts, tlist, wlist, contrib, (int)cap);
        k_gather<<<dim3(N_TOK), 128, 0, stream>>>(contrib, out);
    } else if (tier == 1) {
        k_moe<true><<<dim3(NEXP*8), 512, 0, stream>>>(
            h, hb, ew, counts, tlist, wlist, out, (int)cap);
    } else {
        k_moe<false><<<dim3(NEXP*8), 512, 0, stream>>>(
            h, hb, ew, counts, tlist, wlist, out, (int)cap);
    }
}